// Round 6
// baseline (353.927 us; speedup 1.0000x reference)
//
#include <hip/hip_runtime.h>
#include <hip/hip_cooperative_groups.h>
#include <math.h>

namespace cg = cooperative_groups;

#define N_NODES 16384
#define N_EDGES 524288
#define C_IN    128
#define C_HID   64
#define C_OUT   16
#define CAP     128   // max stored in-edges/node; P(deg>128)~1e-30 for Poisson(32)
#define GRID    1024
#define BLK     256

// ===========================================================================
// Fused cooperative kernel: phase0 zero-cnt + stage W1 | sync |
// phase1 bin edges + GEMM1 | sync | phase2 l1+GEMM2 | sync | phase3 l2+softmax
__global__ __launch_bounds__(BLK, 4) void k_fused(
        const float* __restrict__ x,  const float* __restrict__ W1,
        const float* __restrict__ b1, const float* __restrict__ W2,
        const float* __restrict__ b2, const int* __restrict__ src,
        const int* __restrict__ dst,  int* __restrict__ cnt,
        int* __restrict__ csr,        float* __restrict__ h1,
        float* __restrict__ h2,       float* __restrict__ out) {
    cg::grid_group grid = cg::this_grid();
    __shared__ float smem[9216];   // 36 KB: [0..8191]=sW1(128x64) | [8192..]=sx(8x128)
    int tid = threadIdx.x;
    int bid = blockIdx.x;
    int gtid = bid * BLK + tid;
    int w = tid >> 6, lane = tid & 63;

    // ---- phase 0: zero cnt; stage W1 (no dependency between the two) -------
    if (gtid < N_NODES) cnt[gtid] = 0;
    {
        const float4* W4 = (const float4*)W1;
        float4* sW4 = (float4*)smem;
        for (int i = tid; i < C_IN * C_HID / 4; i += BLK) sW4[i] = W4[i];
    }
    grid.sync();

    // ---- phase 1: bin edges (2/thread) + h1 = x @ W1 (16 nodes/block) ------
    {
        int e = gtid * 2;
        int2 s2 = *(const int2*)&src[e];
        int2 d2 = *(const int2*)&dst[e];
        int slot0 = atomicAdd(&cnt[d2.x], 1);
        int slot1 = atomicAdd(&cnt[d2.y], 1);
        if (slot0 < CAP) csr[d2.x * CAP + slot0] = s2.x;
        if (slot1 < CAP) csr[d2.y * CAP + slot1] = s2.y;

        float* sx = smem + 8192;            // 8 x 128
        for (int half = 0; half < 2; ++half) {
            const float4* x4 = (const float4*)(x + ((size_t)bid * 16 + half * 8) * C_IN);
            float4* sx4 = (float4*)sx;
            __syncthreads();                // prev half's reads done
            for (int i = tid; i < 8 * C_IN / 4; i += BLK) sx4[i] = x4[i];
            __syncthreads();
            float a0 = 0.f, a1 = 0.f;
#pragma unroll 8
            for (int k = 0; k < C_IN; ++k) {
                float wv = smem[k * C_HID + lane];
                a0 = fmaf(sx[w * C_IN + k],       wv, a0);
                a1 = fmaf(sx[(w + 4) * C_IN + k], wv, a1);
            }
            int node0 = bid * 16 + half * 8;
            h1[(node0 + w) * C_HID + lane]     = a0;
            h1[(node0 + w + 4) * C_HID + lane] = a1;
        }
    }
    grid.sync();

    // ---- phase 2: l1 gather + relu + z @ W2 -> h2 (16 nodes/block) ---------
    {
        // restage W2^T into smem[0..1039], stride 65 (bank-conflict pad)
        for (int i = tid; i < C_HID * C_OUT; i += BLK) {
            int k = i >> 4, c = i & 15;
            smem[c * (C_HID + 1) + k] = W2[i];
        }
        __syncthreads();
        float* sz = smem + 1040;            // [4][64] per-wave z rows
        int sub = lane >> 4;                // edge subgroup 0..3
        int cq  = lane & 15;                // channels 4cq..4cq+3
        for (int it = 0; it < 4; ++it) {
            int node = bid * 16 + it * 4 + w;
            int degf = cnt[node];
            int deg = degf < CAP ? degf : CAP;
            int cbase = node * CAP;
            float4 acc = make_float4(0.f, 0.f, 0.f, 0.f);
            for (int j = sub; j < deg; j += 4) {
                int s = csr[cbase + j];
                float iv = rsqrtf((float)cnt[s] + 1.0f);
                const float4 v = *(const float4*)&h1[s * C_HID + 4 * cq];
                acc.x = fmaf(v.x, iv, acc.x);
                acc.y = fmaf(v.y, iv, acc.y);
                acc.z = fmaf(v.z, iv, acc.z);
                acc.w = fmaf(v.w, iv, acc.w);
            }
            acc.x += __shfl_xor(acc.x, 16); acc.y += __shfl_xor(acc.y, 16);
            acc.z += __shfl_xor(acc.z, 16); acc.w += __shfl_xor(acc.w, 16);
            acc.x += __shfl_xor(acc.x, 32); acc.y += __shfl_xor(acc.y, 32);
            acc.z += __shfl_xor(acc.z, 32); acc.w += __shfl_xor(acc.w, 32);

            float ivd = rsqrtf((float)degf + 1.0f);
            float iv2 = ivd * ivd;
            const float4 self = *(const float4*)&h1[node * C_HID + 4 * cq];
            const float4 bb   = *(const float4*)&b1[4 * cq];
            if (lane < 16) {
                sz[w * 64 + 4 * cq]     = fmaxf(fmaf(acc.x, ivd, fmaf(self.x, iv2, bb.x)), 0.f);
                sz[w * 64 + 4 * cq + 1] = fmaxf(fmaf(acc.y, ivd, fmaf(self.y, iv2, bb.y)), 0.f);
                sz[w * 64 + 4 * cq + 2] = fmaxf(fmaf(acc.z, ivd, fmaf(self.z, iv2, bb.z)), 0.f);
                sz[w * 64 + 4 * cq + 3] = fmaxf(fmaf(acc.w, ivd, fmaf(self.w, iv2, bb.w)), 0.f);
            }
            // wave-synchronous LDS exchange (same wave wrote sz[w])
            int c = lane & 15, kg = lane >> 4;
            float p = 0.f;
#pragma unroll
            for (int i = 0; i < 16; ++i) {
                int k = kg * 16 + i;
                p += sz[w * 64 + k] * smem[c * (C_HID + 1) + k];
            }
            p += __shfl_xor(p, 16);
            p += __shfl_xor(p, 32);
            if (kg == 0) h2[node * C_OUT + c] = p;
        }
    }
    grid.sync();

    // ---- phase 3: l2 gather + self + bias + softmax -> out (16 nodes/block)
    {
        int g  = lane >> 2;                 // edge subgroup 0..15
        int cq = lane & 3;                  // channels 4cq..4cq+3
        for (int it = 0; it < 4; ++it) {
            int node = bid * 16 + it * 4 + w;
            int degf = cnt[node];
            int deg = degf < CAP ? degf : CAP;
            int cbase = node * CAP;
            float4 acc = make_float4(0.f, 0.f, 0.f, 0.f);
            for (int j = g; j < deg; j += 16) {
                int s = csr[cbase + j];
                float iv = rsqrtf((float)cnt[s] + 1.0f);
                const float4 v = *(const float4*)&h2[s * C_OUT + 4 * cq];
                acc.x = fmaf(v.x, iv, acc.x);
                acc.y = fmaf(v.y, iv, acc.y);
                acc.z = fmaf(v.z, iv, acc.z);
                acc.w = fmaf(v.w, iv, acc.w);
            }
#pragma unroll
            for (int d = 4; d < 64; d <<= 1) {
                acc.x += __shfl_xor(acc.x, d); acc.y += __shfl_xor(acc.y, d);
                acc.z += __shfl_xor(acc.z, d); acc.w += __shfl_xor(acc.w, d);
            }
            float ivd = rsqrtf((float)degf + 1.0f);
            float iv2 = ivd * ivd;
            const float4 self = *(const float4*)&h2[node * C_OUT + 4 * cq];
            const float4 bb   = *(const float4*)&b2[4 * cq];
            float l0  = fmaf(acc.x, ivd, fmaf(self.x, iv2, bb.x));
            float l1v = fmaf(acc.y, ivd, fmaf(self.y, iv2, bb.y));
            float l2v = fmaf(acc.z, ivd, fmaf(self.z, iv2, bb.z));
            float l3  = fmaf(acc.w, ivd, fmaf(self.w, iv2, bb.w));
            float mx = fmaxf(fmaxf(l0, l1v), fmaxf(l2v, l3));
            mx = fmaxf(mx, __shfl_xor(mx, 1));
            mx = fmaxf(mx, __shfl_xor(mx, 2));
            float e0 = expf(l0 - mx), e1 = expf(l1v - mx);
            float e2 = expf(l2v - mx), e3 = expf(l3 - mx);
            float sum = e0 + e1 + e2 + e3;
            sum += __shfl_xor(sum, 1);
            sum += __shfl_xor(sum, 2);
            float r = 1.0f / sum;
            if (lane < 4) {
                float4 o = make_float4(e0 * r, e1 * r, e2 * r, e3 * r);
                *(float4*)&out[node * C_OUT + 4 * cq] = o;
            }
        }
    }
}

// ===========================================================================
// Fallback path (round-5 proven 4-dispatch chain), used only if the
// cooperative launch is rejected.
__global__ __launch_bounds__(256) void k_gemm1_bin(const float* __restrict__ x,
                                                   const float* __restrict__ W1,
                                                   float* __restrict__ h1,
                                                   const int* __restrict__ src,
                                                   const int* __restrict__ dst,
                                                   int* __restrict__ cnt,
                                                   int* __restrict__ csr) {
    __shared__ float sW[C_IN][C_HID];
    __shared__ float sx[16][C_IN];
    int tid = threadIdx.x;
    int e = (blockIdx.x * 256 + tid) * 2;
    int2 s2 = *(const int2*)&src[e];
    int2 d2 = *(const int2*)&dst[e];
    int slot0 = atomicAdd(&cnt[d2.x], 1);
    int slot1 = atomicAdd(&cnt[d2.y], 1);
    if (slot0 < CAP) csr[d2.x * CAP + slot0] = s2.x;
    if (slot1 < CAP) csr[d2.y * CAP + slot1] = s2.y;

    const float4* W4 = (const float4*)W1;
    float4* sW4 = (float4*)sW;
    for (int i = tid; i < C_IN * C_HID / 4; i += 256) sW4[i] = W4[i];
    const float4* x4 = (const float4*)(x + (size_t)blockIdx.x * 16 * C_IN);
    float4* sx4 = (float4*)sx;
    for (int i = tid; i < 16 * C_IN / 4; i += 256) sx4[i] = x4[i];
    __syncthreads();
    int w = tid >> 6, col = tid & 63;
    float a0 = 0.f, a1 = 0.f, a2 = 0.f, a3 = 0.f;
#pragma unroll 8
    for (int k = 0; k < C_IN; ++k) {
        float wv = sW[k][col];
        a0 = fmaf(sx[w][k],      wv, a0);
        a1 = fmaf(sx[w + 4][k],  wv, a1);
        a2 = fmaf(sx[w + 8][k],  wv, a2);
        a3 = fmaf(sx[w + 12][k], wv, a3);
    }
    int node0 = blockIdx.x * 16;
    h1[(node0 + w) * C_HID + col]      = a0;
    h1[(node0 + w + 4) * C_HID + col]  = a1;
    h1[(node0 + w + 8) * C_HID + col]  = a2;
    h1[(node0 + w + 12) * C_HID + col] = a3;
}

__global__ __launch_bounds__(256) void k_l1(const float* __restrict__ h1,
                                            const int* __restrict__ csr,
                                            const int* __restrict__ cnt,
                                            const float* __restrict__ b1,
                                            const float* __restrict__ W2,
                                            float* __restrict__ h2) {
    __shared__ float sW[C_OUT][C_HID + 1];
    __shared__ float sz[4][C_HID];
    int tid = threadIdx.x;
    for (int i = tid; i < C_HID * C_OUT; i += 256) {
        int k = i >> 4, c = i & 15;
        sW[c][k] = W2[i];
    }
    __syncthreads();
    int w = tid >> 6, lane = tid & 63;
    int node = blockIdx.x * 4 + w;
    int degf = cnt[node];
    int deg = degf < CAP ? degf : CAP;
    int sub = lane >> 4, cq = lane & 15;
    int cbase = node * CAP;
    float4 acc = make_float4(0.f, 0.f, 0.f, 0.f);
    for (int j = sub; j < deg; j += 4) {
        int s = csr[cbase + j];
        float iv = rsqrtf((float)cnt[s] + 1.0f);
        const float4 v = *(const float4*)&h1[s * C_HID + 4 * cq];
        acc.x = fmaf(v.x, iv, acc.x);
        acc.y = fmaf(v.y, iv, acc.y);
        acc.z = fmaf(v.z, iv, acc.z);
        acc.w = fmaf(v.w, iv, acc.w);
    }
    acc.x += __shfl_xor(acc.x, 16); acc.y += __shfl_xor(acc.y, 16);
    acc.z += __shfl_xor(acc.z, 16); acc.w += __shfl_xor(acc.w, 16);
    acc.x += __shfl_xor(acc.x, 32); acc.y += __shfl_xor(acc.y, 32);
    acc.z += __shfl_xor(acc.z, 32); acc.w += __shfl_xor(acc.w, 32);
    float ivd = rsqrtf((float)degf + 1.0f);
    float iv2 = ivd * ivd;
    const float4 self = *(const float4*)&h1[node * C_HID + 4 * cq];
    const float4 bb   = *(const float4*)&b1[4 * cq];
    if (lane < 16) {
        sz[w][4 * cq]     = fmaxf(fmaf(acc.x, ivd, fmaf(self.x, iv2, bb.x)), 0.f);
        sz[w][4 * cq + 1] = fmaxf(fmaf(acc.y, ivd, fmaf(self.y, iv2, bb.y)), 0.f);
        sz[w][4 * cq + 2] = fmaxf(fmaf(acc.z, ivd, fmaf(self.z, iv2, bb.z)), 0.f);
        sz[w][4 * cq + 3] = fmaxf(fmaf(acc.w, ivd, fmaf(self.w, iv2, bb.w)), 0.f);
    }
    int c = lane & 15, kg = lane >> 4;
    float p = 0.f;
#pragma unroll
    for (int i = 0; i < 16; ++i) {
        int k = kg * 16 + i;
        p += sz[w][k] * sW[c][k];
    }
    p += __shfl_xor(p, 16);
    p += __shfl_xor(p, 32);
    if (kg == 0) h2[node * C_OUT + c] = p;
}

__global__ __launch_bounds__(256) void k_l2(const float* __restrict__ h2,
                                            const int* __restrict__ csr,
                                            const int* __restrict__ cnt,
                                            const float* __restrict__ b2,
                                            float* __restrict__ out) {
    int tid = threadIdx.x;
    int w = tid >> 6, lane = tid & 63;
    int node = blockIdx.x * 4 + w;
    int degf = cnt[node];
    int deg = degf < CAP ? degf : CAP;
    int g = lane >> 2, cq = lane & 3;
    int cbase = node * CAP;
    float4 acc = make_float4(0.f, 0.f, 0.f, 0.f);
    for (int j = g; j < deg; j += 16) {
        int s = csr[cbase + j];
        float iv = rsqrtf((float)cnt[s] + 1.0f);
        const float4 v = *(const float4*)&h2[s * C_OUT + 4 * cq];
        acc.x = fmaf(v.x, iv, acc.x);
        acc.y = fmaf(v.y, iv, acc.y);
        acc.z = fmaf(v.z, iv, acc.z);
        acc.w = fmaf(v.w, iv, acc.w);
    }
#pragma unroll
    for (int d = 4; d < 64; d <<= 1) {
        acc.x += __shfl_xor(acc.x, d); acc.y += __shfl_xor(acc.y, d);
        acc.z += __shfl_xor(acc.z, d); acc.w += __shfl_xor(acc.w, d);
    }
    float ivd = rsqrtf((float)degf + 1.0f);
    float iv2 = ivd * ivd;
    const float4 self = *(const float4*)&h2[node * C_OUT + 4 * cq];
    const float4 bb   = *(const float4*)&b2[4 * cq];
    float l0  = fmaf(acc.x, ivd, fmaf(self.x, iv2, bb.x));
    float l1v = fmaf(acc.y, ivd, fmaf(self.y, iv2, bb.y));
    float l2v = fmaf(acc.z, ivd, fmaf(self.z, iv2, bb.z));
    float l3  = fmaf(acc.w, ivd, fmaf(self.w, iv2, bb.w));
    float mx = fmaxf(fmaxf(l0, l1v), fmaxf(l2v, l3));
    mx = fmaxf(mx, __shfl_xor(mx, 1));
    mx = fmaxf(mx, __shfl_xor(mx, 2));
    float e0 = expf(l0 - mx), e1 = expf(l1v - mx);
    float e2 = expf(l2v - mx), e3 = expf(l3 - mx);
    float sum = e0 + e1 + e2 + e3;
    sum += __shfl_xor(sum, 1);
    sum += __shfl_xor(sum, 2);
    float r = 1.0f / sum;
    if (lane < 4) {
        float4 o = make_float4(e0 * r, e1 * r, e2 * r, e3 * r);
        *(float4*)&out[node * C_OUT + 4 * cq] = o;
    }
}

// ===========================================================================
extern "C" void kernel_launch(void* const* d_in, const int* in_sizes, int n_in,
                              void* d_out, int out_size, void* d_ws, size_t ws_size,
                              hipStream_t stream) {
    const float* x    = (const float*)d_in[0];
    const int*   eidx = (const int*)d_in[1];
    // d_in[2] = adj, unused
    const float* W1   = (const float*)d_in[3];
    const float* b1   = (const float*)d_in[4];
    const float* W2   = (const float*)d_in[5];
    const float* b2   = (const float*)d_in[6];
    float* out = (float*)d_out;

    const int* src = eidx;
    const int* dst = eidx + N_EDGES;

    char* ws = (char*)d_ws;
    int*   cnt = (int*)  (ws);                // 64 KB
    int*   csr = (int*)  (ws + (1 << 20));    // 8 MB  (16384 x 128 ints)
    float* h1  = (float*)(ws + (16 << 20));   // 4 MB
    float* h2  = (float*)(ws + (24 << 20));   // 1 MB

    void* args[12] = { (void*)&x, (void*)&W1, (void*)&b1, (void*)&W2,
                       (void*)&b2, (void*)&src, (void*)&dst, (void*)&cnt,
                       (void*)&csr, (void*)&h1, (void*)&h2, (void*)&out };
    hipError_t err = hipLaunchCooperativeKernel((const void*)k_fused,
                                                dim3(GRID), dim3(BLK),
                                                args, 0, stream);
    if (err != hipSuccess) {
        // fallback: proven 4-dispatch path
        hipMemsetAsync(cnt, 0, (size_t)N_NODES * sizeof(int), stream);
        k_gemm1_bin<<<N_NODES / 16, 256, 0, stream>>>(x, W1, h1, src, dst, cnt, csr);
        k_l1<<<N_NODES / 4, 256, 0, stream>>>(h1, csr, cnt, b1, W2, h2);
        k_l2<<<N_NODES / 4, 256, 0, stream>>>(h2, csr, cnt, b2, out);
    }
}

// Round 7
// 83.657 us; speedup vs baseline: 4.2307x; 4.2307x over previous
//
#include <hip/hip_runtime.h>
#include <math.h>

#define N_NODES 16384
#define N_EDGES 524288
#define C_IN    128
#define C_HID   64
#define C_OUT   16
#define CAP     128   // max stored in-edges/node; P(deg>128)~1e-30 for Poisson(32)

// ---------------------------------------------------------------------------
// Zero cnt: 16 blocks x 256 threads x 4 ints = 16384 ints.
__global__ __launch_bounds__(256) void k_zero(int4* __restrict__ cnt4) {
    cnt4[blockIdx.x * 256 + threadIdx.x] = make_int4(0, 0, 0, 0);
}

// ---------------------------------------------------------------------------
// Fused: binned-CSR build (4 edges/thread) + h1 = x @ W1 (32 nodes/block,
// 8 outputs/thread). Grid 512 x 256: 512*1024 = N_EDGES, 512*32 = N_NODES.
__global__ __launch_bounds__(256) void k_gemm1_bin(const float* __restrict__ x,
                                                   const float* __restrict__ W1,
                                                   float* __restrict__ h1,
                                                   const int* __restrict__ src,
                                                   const int* __restrict__ dst,
                                                   int* __restrict__ cnt,
                                                   int* __restrict__ csr) {
    __shared__ float sW[C_IN][C_HID];   // 32 KB
    __shared__ float sx[32][C_IN];      // 16 KB
    int tid = threadIdx.x;
    int e = (blockIdx.x * 256 + tid) * 4;

    int4 s4 = *(const int4*)&src[e];
    int4 d4 = *(const int4*)&dst[e];
    int sl0 = atomicAdd(&cnt[d4.x], 1);
    int sl1 = atomicAdd(&cnt[d4.y], 1);
    int sl2 = atomicAdd(&cnt[d4.z], 1);
    int sl3 = atomicAdd(&cnt[d4.w], 1);
    if (sl0 < CAP) csr[d4.x * CAP + sl0] = s4.x;
    if (sl1 < CAP) csr[d4.y * CAP + sl1] = s4.y;
    if (sl2 < CAP) csr[d4.z * CAP + sl2] = s4.z;
    if (sl3 < CAP) csr[d4.w * CAP + sl3] = s4.w;

    const float4* W4 = (const float4*)W1;
    float4* sW4 = (float4*)sW;
    for (int i = tid; i < C_IN * C_HID / 4; i += 256) sW4[i] = W4[i];
    const float4* x4 = (const float4*)(x + (size_t)blockIdx.x * 32 * C_IN);
    float4* sx4 = (float4*)sx;
    for (int i = tid; i < 32 * C_IN / 4; i += 256) sx4[i] = x4[i];
    __syncthreads();

    int w = tid >> 6, col = tid & 63;
    float a[8] = {0.f, 0.f, 0.f, 0.f, 0.f, 0.f, 0.f, 0.f};
#pragma unroll 4
    for (int k = 0; k < C_IN; ++k) {
        float wv = sW[k][col];
#pragma unroll
        for (int i = 0; i < 8; ++i)
            a[i] = fmaf(sx[w + 4 * i][k], wv, a[i]);
    }
    int node0 = blockIdx.x * 32;
#pragma unroll
    for (int i = 0; i < 8; ++i)
        h1[(node0 + w + 4 * i) * C_HID + col] = a[i];
}

// ---------------------------------------------------------------------------
// Layer 1: 1024 blocks, 4 waves/block, 4 nodes per wave (sequential).
// lane = [edge-sub 2b | chan-quad 4b]; gather h1 rows from binned CSR,
// on-the-fly inv = rsqrt(cnt+1), self term + bias, relu, z @ W2 -> h2.
__global__ __launch_bounds__(256) void k_l1(const float* __restrict__ h1,
                                            const int* __restrict__ csr,
                                            const int* __restrict__ cnt,
                                            const float* __restrict__ b1,
                                            const float* __restrict__ W2,
                                            float* __restrict__ h2) {
    __shared__ float sW[C_OUT][C_HID + 1];
    __shared__ float sz[4][C_HID];
    int tid = threadIdx.x;
    for (int i = tid; i < C_HID * C_OUT; i += 256) {
        int k = i >> 4, c = i & 15;
        sW[c][k] = W2[i];
    }
    __syncthreads();

    int w = tid >> 6, lane = tid & 63;
    int sub = lane >> 4;                       // edge subgroup 0..3
    int cq  = lane & 15;                       // channels 4cq..4cq+3
    int c = lane & 15, kg = lane >> 4;

    for (int it = 0; it < 4; ++it) {
        int node = blockIdx.x * 16 + it * 4 + w;
        int degf = cnt[node];                  // full degree (for norm)
        int deg = degf < CAP ? degf : CAP;     // stored edges
        int cbase = node * CAP;

        float4 acc = make_float4(0.f, 0.f, 0.f, 0.f);
        for (int j = sub; j < deg; j += 4) {
            int s = csr[cbase + j];            // 16 lanes same addr: broadcast
            float iv = rsqrtf((float)cnt[s] + 1.0f);
            const float4 v = *(const float4*)&h1[s * C_HID + 4 * cq];
            acc.x = fmaf(v.x, iv, acc.x);
            acc.y = fmaf(v.y, iv, acc.y);
            acc.z = fmaf(v.z, iv, acc.z);
            acc.w = fmaf(v.w, iv, acc.w);
        }
        acc.x += __shfl_xor(acc.x, 16); acc.y += __shfl_xor(acc.y, 16);
        acc.z += __shfl_xor(acc.z, 16); acc.w += __shfl_xor(acc.w, 16);
        acc.x += __shfl_xor(acc.x, 32); acc.y += __shfl_xor(acc.y, 32);
        acc.z += __shfl_xor(acc.z, 32); acc.w += __shfl_xor(acc.w, 32);

        float ivd = rsqrtf((float)degf + 1.0f);
        float iv2 = ivd * ivd;
        const float4 self = *(const float4*)&h1[node * C_HID + 4 * cq];
        const float4 bb   = *(const float4*)&b1[4 * cq];
        if (lane < 16) {
            sz[w][4 * cq]     = fmaxf(fmaf(acc.x, ivd, fmaf(self.x, iv2, bb.x)), 0.f);
            sz[w][4 * cq + 1] = fmaxf(fmaf(acc.y, ivd, fmaf(self.y, iv2, bb.y)), 0.f);
            sz[w][4 * cq + 2] = fmaxf(fmaf(acc.z, ivd, fmaf(self.z, iv2, bb.z)), 0.f);
            sz[w][4 * cq + 3] = fmaxf(fmaf(acc.w, ivd, fmaf(self.w, iv2, bb.w)), 0.f);
        }
        // wave-synchronous LDS exchange (same wave wrote sz[w])
        float p = 0.f;
#pragma unroll
        for (int i = 0; i < 16; ++i) {
            int k = kg * 16 + i;
            p += sz[w][k] * sW[c][k];
        }
        p += __shfl_xor(p, 16);
        p += __shfl_xor(p, 32);
        if (kg == 0) h2[node * C_OUT + c] = p;
    }
}

// ---------------------------------------------------------------------------
// Layer 2: 1024 blocks, 4 waves/block, 4 nodes per wave (sequential).
// lane = [edge-sub 4b | chan-quad 2b]; gather h2 rows, self + bias + softmax.
__global__ __launch_bounds__(256) void k_l2(const float* __restrict__ h2,
                                            const int* __restrict__ csr,
                                            const int* __restrict__ cnt,
                                            const float* __restrict__ b2,
                                            float* __restrict__ out) {
    int tid = threadIdx.x;
    int w = tid >> 6, lane = tid & 63;
    int g  = lane >> 2;      // edge subgroup 0..15
    int cq = lane & 3;       // channels 4cq..4cq+3

    for (int it = 0; it < 4; ++it) {
        int node = blockIdx.x * 16 + it * 4 + w;
        int degf = cnt[node];
        int deg = degf < CAP ? degf : CAP;
        int cbase = node * CAP;

        float4 acc = make_float4(0.f, 0.f, 0.f, 0.f);
        for (int j = g; j < deg; j += 16) {
            int s = csr[cbase + j];                 // 4 lanes same addr
            float iv = rsqrtf((float)cnt[s] + 1.0f);
            const float4 v = *(const float4*)&h2[s * C_OUT + 4 * cq];
            acc.x = fmaf(v.x, iv, acc.x);
            acc.y = fmaf(v.y, iv, acc.y);
            acc.z = fmaf(v.z, iv, acc.z);
            acc.w = fmaf(v.w, iv, acc.w);
        }
#pragma unroll
        for (int d = 4; d < 64; d <<= 1) {
            acc.x += __shfl_xor(acc.x, d); acc.y += __shfl_xor(acc.y, d);
            acc.z += __shfl_xor(acc.z, d); acc.w += __shfl_xor(acc.w, d);
        }

        float ivd = rsqrtf((float)degf + 1.0f);
        float iv2 = ivd * ivd;
        const float4 self = *(const float4*)&h2[node * C_OUT + 4 * cq];
        const float4 bb   = *(const float4*)&b2[4 * cq];
        float l0  = fmaf(acc.x, ivd, fmaf(self.x, iv2, bb.x));
        float l1v = fmaf(acc.y, ivd, fmaf(self.y, iv2, bb.y));
        float l2v = fmaf(acc.z, ivd, fmaf(self.z, iv2, bb.z));
        float l3  = fmaf(acc.w, ivd, fmaf(self.w, iv2, bb.w));

        float mx = fmaxf(fmaxf(l0, l1v), fmaxf(l2v, l3));
        mx = fmaxf(mx, __shfl_xor(mx, 1));
        mx = fmaxf(mx, __shfl_xor(mx, 2));
        float e0 = expf(l0 - mx), e1 = expf(l1v - mx);
        float e2 = expf(l2v - mx), e3 = expf(l3 - mx);
        float sum = e0 + e1 + e2 + e3;
        sum += __shfl_xor(sum, 1);
        sum += __shfl_xor(sum, 2);
        float r = 1.0f / sum;
        if (lane < 4) {
            float4 o = make_float4(e0 * r, e1 * r, e2 * r, e3 * r);
            *(float4*)&out[node * C_OUT + 4 * cq] = o;
        }
    }
}

// ---------------------------------------------------------------------------
extern "C" void kernel_launch(void* const* d_in, const int* in_sizes, int n_in,
                              void* d_out, int out_size, void* d_ws, size_t ws_size,
                              hipStream_t stream) {
    const float* x    = (const float*)d_in[0];
    const int*   eidx = (const int*)d_in[1];
    // d_in[2] = adj, unused
    const float* W1   = (const float*)d_in[3];
    const float* b1   = (const float*)d_in[4];
    const float* W2   = (const float*)d_in[5];
    const float* b2   = (const float*)d_in[6];
    float* out = (float*)d_out;

    const int* src = eidx;
    const int* dst = eidx + N_EDGES;

    char* ws = (char*)d_ws;
    int*   cnt = (int*)  (ws);                // 64 KB
    int*   csr = (int*)  (ws + (1 << 20));    // 8 MB  (16384 x 128 ints)
    float* h1  = (float*)(ws + (16 << 20));   // 4 MB
    float* h2  = (float*)(ws + (24 << 20));   // 1 MB

    k_zero<<<16, 256, 0, stream>>>((int4*)cnt);
    k_gemm1_bin<<<N_NODES / 32, 256, 0, stream>>>(x, W1, h1, src, dst, cnt, csr);
    k_l1<<<N_NODES / 16, 256, 0, stream>>>(h1, csr, cnt, b1, W2, h2);
    k_l2<<<N_NODES / 16, 256, 0, stream>>>(h2, csr, cnt, b2, out);
}

// Round 8
// 74.381 us; speedup vs baseline: 4.7583x; 1.1247x over previous
//
#include <hip/hip_runtime.h>
#include <math.h>

#define N_NODES 16384
#define N_EDGES 524288
#define C_IN    128
#define C_HID   64
#define C_OUT   16
#define CAP     128   // max stored in-edges/node; P(deg>128)~1e-30 for Poisson(32)

// ---------------------------------------------------------------------------
// Fused: binned-CSR build (2 edges/thread) + h1 = x @ W1 (16 nodes/block,
// 4 outputs/thread). Grid 1024 x 256. W1 staged in quad-k transposed layout:
// sWt word ((k>>2)*64 + col)*4 + (k&3)  ->  inner loop does ONE conflict-free
// contiguous ds_read_b128 + 4 broadcast b128 per 4 k-steps (4x fewer LDS ops).
__global__ __launch_bounds__(256) void k_gemm1_bin(const float* __restrict__ x,
                                                   const float* __restrict__ W1,
                                                   float* __restrict__ h1,
                                                   const int* __restrict__ src,
                                                   const int* __restrict__ dst,
                                                   int* __restrict__ cnt,
                                                   int* __restrict__ csr) {
    __shared__ float sWt[C_IN * C_HID];   // 32 KB, quad-k transposed
    __shared__ float sx[16 * C_IN];       // 8 KB
    int tid = threadIdx.x;
    int e = (blockIdx.x * 256 + tid) * 2;

    int2 s2 = *(const int2*)&src[e];
    int2 d2 = *(const int2*)&dst[e];
    int sl0 = atomicAdd(&cnt[d2.x], 1);
    int sl1 = atomicAdd(&cnt[d2.y], 1);
    if (sl0 < CAP) csr[d2.x * CAP + sl0] = s2.x;
    if (sl1 < CAP) csr[d2.y * CAP + sl1] = s2.y;

    // stage W1 (coalesced float4 reads, transposed quad-k LDS writes)
    const float4* W4 = (const float4*)W1;
    for (int i = tid; i < C_IN * C_HID / 4; i += 256) {
        float4 q = W4[i];                 // = W1[k][4c4 .. 4c4+3]
        int k  = i >> 4;
        int c4 = i & 15;
        int base = ((k >> 2) * C_HID + 4 * c4) * 4 + (k & 3);
        sWt[base]      = q.x;
        sWt[base + 4]  = q.y;
        sWt[base + 8]  = q.z;
        sWt[base + 12] = q.w;
    }
    const float4* x4 = (const float4*)(x + (size_t)blockIdx.x * 16 * C_IN);
    float4* sx4 = (float4*)sx;
    for (int i = tid; i < 16 * C_IN / 4; i += 256) sx4[i] = x4[i];
    __syncthreads();

    int w = tid >> 6, col = tid & 63;
    const float4* sW4r = (const float4*)sWt;   // sW4r[k4*64 + col]
    float a0 = 0.f, a1 = 0.f, a2 = 0.f, a3 = 0.f;
#pragma unroll 8
    for (int k4 = 0; k4 < C_IN / 4; ++k4) {
        float4 wv = sW4r[k4 * C_HID + col];                      // contiguous
        float4 xa = *(const float4*)&sx[w * C_IN + 4 * k4];      // broadcast
        float4 xb = *(const float4*)&sx[(w + 4) * C_IN + 4 * k4];
        float4 xc = *(const float4*)&sx[(w + 8) * C_IN + 4 * k4];
        float4 xd = *(const float4*)&sx[(w + 12) * C_IN + 4 * k4];
        a0 = fmaf(xa.x, wv.x, fmaf(xa.y, wv.y, fmaf(xa.z, wv.z, fmaf(xa.w, wv.w, a0))));
        a1 = fmaf(xb.x, wv.x, fmaf(xb.y, wv.y, fmaf(xb.z, wv.z, fmaf(xb.w, wv.w, a1))));
        a2 = fmaf(xc.x, wv.x, fmaf(xc.y, wv.y, fmaf(xc.z, wv.z, fmaf(xc.w, wv.w, a2))));
        a3 = fmaf(xd.x, wv.x, fmaf(xd.y, wv.y, fmaf(xd.z, wv.z, fmaf(xd.w, wv.w, a3))));
    }
    int node0 = blockIdx.x * 16;
    h1[(node0 + w) * C_HID + col]      = a0;
    h1[(node0 + w + 4) * C_HID + col]  = a1;
    h1[(node0 + w + 8) * C_HID + col]  = a2;
    h1[(node0 + w + 12) * C_HID + col] = a3;
}

// ---------------------------------------------------------------------------
// Layer 1: per node (one wave), r5 mapping (4096 blocks x 4 waves).
// lane = [edge-sub 2b | chan-quad 4b]. 1-deep software-pipelined gather:
// next iteration's csr/cnt/h1 loads issue before current values are consumed.
__global__ __launch_bounds__(256) void k_l1(const float* __restrict__ h1,
                                            const int* __restrict__ csr,
                                            const int* __restrict__ cnt,
                                            const float* __restrict__ b1,
                                            const float* __restrict__ W2,
                                            float* __restrict__ h2) {
    __shared__ float sW[C_OUT][C_HID + 1];
    __shared__ float sz[4][C_HID];
    int tid = threadIdx.x;
    for (int i = tid; i < C_HID * C_OUT; i += 256) {
        int k = i >> 4, c = i & 15;
        sW[c][k] = W2[i];
    }
    __syncthreads();

    int w = tid >> 6, lane = tid & 63;
    int node = blockIdx.x * 4 + w;
    int degf = cnt[node];                      // full degree (for norm)
    int deg = degf < CAP ? degf : CAP;         // stored edges
    int sub = lane >> 4;                       // edge subgroup 0..3
    int cq  = lane & 15;                       // channels 4cq..4cq+3
    int cbase = node * CAP;

    float4 acc = make_float4(0.f, 0.f, 0.f, 0.f);
    if (deg > 0) {
        int jmax = deg - 1;
        int j = sub;
        int jc = j <= jmax ? j : jmax;
        int s = csr[cbase + jc];
        float dc = (float)cnt[s];
        float4 v = *(const float4*)&h1[s * C_HID + 4 * cq];
        bool valid = j <= jmax;
        while (true) {
            int jn = j + 4;
            int jcn = jn <= jmax ? jn : jmax;
            int sn = csr[cbase + jcn];                              // prefetch
            float dn = (float)cnt[sn];                              // prefetch
            float4 vn = *(const float4*)&h1[sn * C_HID + 4 * cq];   // prefetch
            float iv = valid ? rsqrtf(dc + 1.0f) : 0.f;
            acc.x = fmaf(v.x, iv, acc.x);
            acc.y = fmaf(v.y, iv, acc.y);
            acc.z = fmaf(v.z, iv, acc.z);
            acc.w = fmaf(v.w, iv, acc.w);
            valid = jn <= jmax;
            if (!__any(valid)) break;
            j = jn; s = sn; dc = dn; v = vn;
        }
    }
    acc.x += __shfl_xor(acc.x, 16); acc.y += __shfl_xor(acc.y, 16);
    acc.z += __shfl_xor(acc.z, 16); acc.w += __shfl_xor(acc.w, 16);
    acc.x += __shfl_xor(acc.x, 32); acc.y += __shfl_xor(acc.y, 32);
    acc.z += __shfl_xor(acc.z, 32); acc.w += __shfl_xor(acc.w, 32);

    float ivd = rsqrtf((float)degf + 1.0f);
    float iv2 = ivd * ivd;
    const float4 self = *(const float4*)&h1[node * C_HID + 4 * cq];
    const float4 bb   = *(const float4*)&b1[4 * cq];
    if (lane < 16) {
        sz[w][4 * cq]     = fmaxf(fmaf(acc.x, ivd, fmaf(self.x, iv2, bb.x)), 0.f);
        sz[w][4 * cq + 1] = fmaxf(fmaf(acc.y, ivd, fmaf(self.y, iv2, bb.y)), 0.f);
        sz[w][4 * cq + 2] = fmaxf(fmaf(acc.z, ivd, fmaf(self.z, iv2, bb.z)), 0.f);
        sz[w][4 * cq + 3] = fmaxf(fmaf(acc.w, ivd, fmaf(self.w, iv2, bb.w)), 0.f);
    }
    // wave-synchronous LDS exchange (same wave wrote sz[w])
    int c = lane & 15, kg = lane >> 4;
    float p = 0.f;
#pragma unroll
    for (int i = 0; i < 16; ++i) {
        int k = kg * 16 + i;
        p += sz[w][k] * sW[c][k];
    }
    p += __shfl_xor(p, 16);
    p += __shfl_xor(p, 32);
    if (kg == 0) h2[node * C_OUT + c] = p;
}

// ---------------------------------------------------------------------------
// Layer 2: per node (one wave), r5 mapping. lane = [edge-sub 4b | chan-quad
// 2b]; gather h2 rows (16 edges per float4 wave-load), self + bias + softmax.
__global__ __launch_bounds__(256) void k_l2(const float* __restrict__ h2,
                                            const int* __restrict__ csr,
                                            const int* __restrict__ cnt,
                                            const float* __restrict__ b2,
                                            float* __restrict__ out) {
    int tid = threadIdx.x;
    int w = tid >> 6, lane = tid & 63;
    int node = blockIdx.x * 4 + w;
    int degf = cnt[node];
    int deg = degf < CAP ? degf : CAP;
    int g  = lane >> 2;      // edge subgroup 0..15
    int cq = lane & 3;       // channels 4cq..4cq+3
    int cbase = node * CAP;

    float4 acc = make_float4(0.f, 0.f, 0.f, 0.f);
    for (int j = g; j < deg; j += 16) {
        int s = csr[cbase + j];                 // 4 lanes same addr
        float iv = rsqrtf((float)cnt[s] + 1.0f);
        const float4 v = *(const float4*)&h2[s * C_OUT + 4 * cq];
        acc.x = fmaf(v.x, iv, acc.x);
        acc.y = fmaf(v.y, iv, acc.y);
        acc.z = fmaf(v.z, iv, acc.z);
        acc.w = fmaf(v.w, iv, acc.w);
    }
#pragma unroll
    for (int d = 4; d < 64; d <<= 1) {
        acc.x += __shfl_xor(acc.x, d); acc.y += __shfl_xor(acc.y, d);
        acc.z += __shfl_xor(acc.z, d); acc.w += __shfl_xor(acc.w, d);
    }

    float ivd = rsqrtf((float)degf + 1.0f);
    float iv2 = ivd * ivd;
    const float4 self = *(const float4*)&h2[node * C_OUT + 4 * cq];
    const float4 bb   = *(const float4*)&b2[4 * cq];
    float l0  = fmaf(acc.x, ivd, fmaf(self.x, iv2, bb.x));
    float l1v = fmaf(acc.y, ivd, fmaf(self.y, iv2, bb.y));
    float l2v = fmaf(acc.z, ivd, fmaf(self.z, iv2, bb.z));
    float l3  = fmaf(acc.w, ivd, fmaf(self.w, iv2, bb.w));

    float mx = fmaxf(fmaxf(l0, l1v), fmaxf(l2v, l3));
    mx = fmaxf(mx, __shfl_xor(mx, 1));
    mx = fmaxf(mx, __shfl_xor(mx, 2));
    float e0 = expf(l0 - mx), e1 = expf(l1v - mx);
    float e2 = expf(l2v - mx), e3 = expf(l3 - mx);
    float sum = e0 + e1 + e2 + e3;
    sum += __shfl_xor(sum, 1);
    sum += __shfl_xor(sum, 2);
    float r = 1.0f / sum;
    if (lane < 4) {
        float4 o = make_float4(e0 * r, e1 * r, e2 * r, e3 * r);
        *(float4*)&out[node * C_OUT + 4 * cq] = o;
    }
}

// ---------------------------------------------------------------------------
extern "C" void kernel_launch(void* const* d_in, const int* in_sizes, int n_in,
                              void* d_out, int out_size, void* d_ws, size_t ws_size,
                              hipStream_t stream) {
    const float* x    = (const float*)d_in[0];
    const int*   eidx = (const int*)d_in[1];
    // d_in[2] = adj, unused
    const float* W1   = (const float*)d_in[3];
    const float* b1   = (const float*)d_in[4];
    const float* W2   = (const float*)d_in[5];
    const float* b2   = (const float*)d_in[6];
    float* out = (float*)d_out;

    const int* src = eidx;
    const int* dst = eidx + N_EDGES;

    char* ws = (char*)d_ws;
    int*   cnt = (int*)  (ws);                // 64 KB
    int*   csr = (int*)  (ws + (1 << 20));    // 8 MB  (16384 x 128 ints)
    float* h1  = (float*)(ws + (16 << 20));   // 4 MB
    float* h2  = (float*)(ws + (24 << 20));   // 1 MB

    hipMemsetAsync(cnt, 0, (size_t)N_NODES * sizeof(int), stream);

    k_gemm1_bin<<<N_NODES / 16, 256, 0, stream>>>(x, W1, h1, src, dst, cnt, csr);
    k_l1<<<N_NODES / 4, 256, 0, stream>>>(h1, csr, cnt, b1, W2, h2);
    k_l2<<<N_NODES / 4, 256, 0, stream>>>(h2, csr, cnt, b2, out);
}